// Round 3
// baseline (504.533 us; speedup 1.0000x reference)
//
#include <hip/hip_runtime.h>
#include <hip/hip_bf16.h>

#define PI_F 3.14159265358979323846f

typedef float fvec4 __attribute__((ext_vector_type(4)));

// ---------------------------------------------------------------------------
// Kernel 1: per-batch matrix build + analytic 3x3 (affine) inverse.
// ---------------------------------------------------------------------------
__global__ void build_mats_kernel(const float* __restrict__ fc2,
                                  float* __restrict__ mat_out,
                                  float* __restrict__ inv_out,
                                  int B) {
    int b = blockIdx.x * blockDim.x + threadIdx.x;
    if (b >= B) return;
    const float* f = fc2 + b * 7;
    float theta = fminf(fmaxf(f[0] * 0.3f, -1.f), 1.f) * PI_F;
    float sx    = fminf(fmaxf(f[1] * 0.3f + 1.f, 0.f), 5.f);
    float sy    = fminf(fmaxf(f[2] * 0.3f + 1.f, 0.f), 5.f);
    float tx    = f[3] * 0.3f;
    float ty    = f[4] * 0.3f;
    float shxy  = fminf(fmaxf(f[5] * 0.3f, -1.f), 1.f) * PI_F;
    float shyx  = fminf(fmaxf(f[6] * 0.3f, -1.f), 1.f) * PI_F;

    float c = cosf(theta), s = sinf(theta);
    float m00 =  sx * c + shxy * sy * s;
    float m01 = -sx * s + shxy * sy * c;
    float m02 = tx;
    float m10 = shyx * sx * c + sy * s;
    float m11 = -shyx * sx * s + sy * c;
    float m12 = ty;

    float* m = mat_out + b * 9;
    m[0] = m00; m[1] = m01; m[2] = m02;
    m[3] = m10; m[4] = m11; m[5] = m12;
    m[6] = 0.f; m[7] = 0.f; m[8] = 1.f;

    float det = m00 * m11 - m01 * m10;
    float id  = 1.f / det;
    float i00 =  m11 * id, i01 = -m01 * id;
    float i10 = -m10 * id, i11 =  m00 * id;
    float i02 = -(i00 * m02 + i01 * m12);
    float i12 = -(i10 * m02 + i11 * m12);

    float* im = inv_out + b * 9;
    im[0] = i00; im[1] = i01; im[2] = i02;
    im[3] = i10; im[4] = i11; im[5] = i12;
    im[6] = 0.f; im[7] = 0.f; im[8] = 1.f;
}

// ---------------------------------------------------------------------------
// Kernel 2: one thread per 1x4 output strip (4 consecutive w).
//  - 16 independent gather loads in flight per channel iteration (MLP)
//  - fvec4 nontemporal 16B stores for transformed + grids (no L2 pollution)
//  - b = blockIdx.z wave-uniform -> matrix loads are scalar
// ---------------------------------------------------------------------------
__global__ __launch_bounds__(256) void affine_main_kernel(
    const float* __restrict__ src,
    const float* __restrict__ mat,
    const float* __restrict__ inv_mat,
    float* __restrict__ transformed,
    float* __restrict__ grid_out,
    float* __restrict__ inv_grid_out)
{
    const int W = 512, H = 512, C = 4;
    int w0 = threadIdx.x * 4;                 // 0,4,...,508  (128 threads in x)
    int h  = blockIdx.y * 2 + threadIdx.y;    // 2 rows per block
    int b  = blockIdx.z;

    const float* m  = mat + b * 9;
    const float* im = inv_mat + b * 9;
    float m00 = m[0],  m01 = m[1],  m02 = m[2];
    float m10 = m[3],  m11 = m[4],  m12 = m[5];
    float i00 = im[0], i01 = im[1], i02 = im[2];
    float i10 = im[3], i11 = im[4], i12 = im[5];

    float ys = (2.f * (float)h + 1.f) * (1.f / (float)H) - 1.f;
    float gyc  = m01 * ys + m02;   // per-row constants (x-part added per pixel)
    float gyc2 = m11 * ys + m12;
    float iyc  = i01 * ys + i02;
    float iyc2 = i11 * ys + i12;

    float gx[4], gy[4], igx[4], igy[4];
    int   off[4][4];
    float wt[4][4];

    #pragma unroll
    for (int p = 0; p < 4; ++p) {
        float xs = (2.f * (float)(w0 + p) + 1.f) * (1.f / (float)W) - 1.f;
        gx[p]  = m00 * xs + gyc;
        gy[p]  = m10 * xs + gyc2;
        igx[p] = i00 * xs + iyc;
        igy[p] = i10 * xs + iyc2;

        float ix = ((gx[p] + 1.f) * (float)W - 1.f) * 0.5f;
        float iy = ((gy[p] + 1.f) * (float)H - 1.f) * 0.5f;
        float x0f = floorf(ix), y0f = floorf(iy);
        float wx = ix - x0f, wy = iy - y0f;
        int x0 = (int)x0f, y0 = (int)y0f;
        int x1 = x0 + 1,   y1 = y0 + 1;

        bool vx0 = (x0 >= 0) && (x0 < W);
        bool vx1 = (x1 >= 0) && (x1 < W);
        bool vy0 = (y0 >= 0) && (y0 < H);
        bool vy1 = (y1 >= 0) && (y1 < H);
        int cx0 = min(max(x0, 0), W - 1), cx1 = min(max(x1, 0), W - 1);
        int cy0 = min(max(y0, 0), H - 1), cy1 = min(max(y1, 0), H - 1);

        wt[p][0] = (1.f - wx) * (1.f - wy) * ((vx0 && vy0) ? 1.f : 0.f);
        wt[p][1] = wx * (1.f - wy)         * ((vx1 && vy0) ? 1.f : 0.f);
        wt[p][2] = (1.f - wx) * wy         * ((vx0 && vy1) ? 1.f : 0.f);
        wt[p][3] = wx * wy                 * ((vx1 && vy1) ? 1.f : 0.f);

        off[p][0] = cy0 * W + cx0;
        off[p][1] = cy0 * W + cx1;
        off[p][2] = cy1 * W + cx0;
        off[p][3] = cy1 * W + cx1;
    }

    // Grid stores: float2 pairs packed into 16B vectors (aligned: w0 % 4 == 0)
    size_t pix = ((size_t)b * H + h) * W + w0;   // float2 element index
    fvec4* gq  = (fvec4*)(grid_out     + pix * 2);
    fvec4* igq = (fvec4*)(inv_grid_out + pix * 2);
    fvec4 g0  = {gx[0],  gy[0],  gx[1],  gy[1]};
    fvec4 g1  = {gx[2],  gy[2],  gx[3],  gy[3]};
    fvec4 ig0 = {igx[0], igy[0], igx[1], igy[1]};
    fvec4 ig1 = {igx[2], igy[2], igx[3], igy[3]};
    __builtin_nontemporal_store(g0,  gq);
    __builtin_nontemporal_store(g1,  gq + 1);
    __builtin_nontemporal_store(ig0, igq);
    __builtin_nontemporal_store(ig1, igq + 1);

    const float* sb = src + (size_t)b * C * H * W;
    #pragma unroll
    for (int c = 0; c < C; ++c) {
        const float* sc = sb + (size_t)c * H * W;
        // 16 independent loads — keep all in flight
        float r00 = sc[off[0][0]], r01 = sc[off[0][1]], r02 = sc[off[0][2]], r03 = sc[off[0][3]];
        float r10 = sc[off[1][0]], r11 = sc[off[1][1]], r12 = sc[off[1][2]], r13 = sc[off[1][3]];
        float r20 = sc[off[2][0]], r21 = sc[off[2][1]], r22 = sc[off[2][2]], r23 = sc[off[2][3]];
        float r30 = sc[off[3][0]], r31 = sc[off[3][1]], r32 = sc[off[3][2]], r33 = sc[off[3][3]];

        fvec4 v;
        v.x = r00 * wt[0][0] + r01 * wt[0][1] + r02 * wt[0][2] + r03 * wt[0][3];
        v.y = r10 * wt[1][0] + r11 * wt[1][1] + r12 * wt[1][2] + r13 * wt[1][3];
        v.z = r20 * wt[2][0] + r21 * wt[2][1] + r22 * wt[2][2] + r23 * wt[2][3];
        v.w = r30 * wt[3][0] + r31 * wt[3][1] + r32 * wt[3][2] + r33 * wt[3][3];

        fvec4* dst = (fvec4*)(transformed + (((size_t)b * C + c) * H + h) * W + w0);
        __builtin_nontemporal_store(v, dst);
    }
}

extern "C" void kernel_launch(void* const* d_in, const int* in_sizes, int n_in,
                              void* d_out, int out_size, void* d_ws, size_t ws_size,
                              hipStream_t stream) {
    const float* src = (const float*)d_in[0];   // (32,4,512,512) f32
    const float* fc2 = (const float*)d_in[1];   // (32,7) f32

    const int B = 32, C = 4, H = 512, W = 512;
    float* out = (float*)d_out;

    float* transformed  = out;                                   // 33,554,432
    float* mat_out      = out + (size_t)B * C * H * W;           // +288
    float* inv_out      = mat_out + (size_t)B * 9;               // +288
    float* grid_out     = inv_out + (size_t)B * 9;               // +16,777,216
    float* inv_grid_out = grid_out + (size_t)B * H * W * 2;      // +16,777,216

    build_mats_kernel<<<1, 64, 0, stream>>>(fc2, mat_out, inv_out, B);

    // 128 threads x-dim (4 px each = 512), 2 rows per block
    dim3 grid(1, H / 2, B);
    dim3 block(128, 2);
    affine_main_kernel<<<grid, block, 0, stream>>>(src, mat_out, inv_out,
                                                   transformed, grid_out, inv_grid_out);
}